// Round 1
// baseline (1391.028 us; speedup 1.0000x reference)
//
#include <hip/hip_runtime.h>
#include <math.h>

#define B_  16
#define P_  10000
#define NB_ 10

// ---------------- Kernel 1: T = R(logr) @ S, per (b,p) ----------------
__global__ void ftoT_kernel(const float* __restrict__ f, float* __restrict__ Tm) {
    int t = blockIdx.x * blockDim.x + threadIdx.x;
    if (t >= B_ * P_) return;
    const float* fp = f + (size_t)t * 9;
    float x = fp[0], y = fp[1], z = fp[2];
    float s3 = fp[3], s4 = fp[4], s5 = fp[5], s6 = fp[6], s7 = fp[7], s8 = fp[8];
    float th2 = x * x + y * y + z * z;
    float R00, R01, R02, R10, R11, R12, R20, R21, R22;
    if (th2 == 0.0f) {
        R00 = 1; R01 = 0; R02 = 0;
        R10 = 0; R11 = 1; R12 = 0;
        R20 = 0; R21 = 0; R22 = 1;
    } else {
        float theta = sqrtf(th2);
        float inv = 1.0f / theta;
        float kx = x * inv, ky = y * inv, kz = z * inv;
        float st = sinf(theta);
        float omc = 1.0f - cosf(theta);
        // Kn = [[0,kx,ky],[-kx,0,kz],[-ky,-kz,0]] per reference K layout
        R00 = 1.0f - omc * (kx * kx + ky * ky);
        R01 = kx * st - omc * (ky * kz);
        R02 = ky * st + omc * (kx * kz);
        R10 = -kx * st - omc * (ky * kz);
        R11 = 1.0f - omc * (kx * kx + kz * kz);
        R12 = kz * st - omc * (kx * ky);
        R20 = -ky * st + omc * (kx * kz);
        R21 = -kz * st - omc * (kx * ky);
        R22 = 1.0f - omc * (ky * ky + kz * kz);
    }
    float* o = Tm + (size_t)t * 9;
    o[0] = R00 * s3 + R01 * s4 + R02 * s5;
    o[1] = R00 * s4 + R01 * s6 + R02 * s7;
    o[2] = R00 * s5 + R01 * s7 + R02 * s8;
    o[3] = R10 * s3 + R11 * s4 + R12 * s5;
    o[4] = R10 * s4 + R11 * s6 + R12 * s7;
    o[5] = R10 * s5 + R11 * s7 + R12 * s8;
    o[6] = R20 * s3 + R21 * s4 + R22 * s5;
    o[7] = R20 * s4 + R21 * s6 + R22 * s7;
    o[8] = R20 * s5 + R21 * s7 + R22 * s8;
}

// ------- Kernel 2: bvec[b,p] = sum_n T_nb @ vdiff[p,n] + T_own @ sum_n vdiff[p,n]
// Output transposed: bvecT[(b*3+d)*P + p] for aligned float4 reads in GEMM.
__global__ void bvec_kernel(const float* __restrict__ Tm, const int* __restrict__ nb,
                            const float* __restrict__ vdiff, float* __restrict__ bvecT) {
    int t = blockIdx.x * blockDim.x + threadIdx.x;
    if (t >= B_ * P_) return;
    int b = t / P_;
    int p = t - b * P_;
    const float* Town = Tm + (size_t)t * 9;
    float a0 = 0, a1 = 0, a2 = 0, vs0 = 0, vs1 = 0, vs2 = 0;
#pragma unroll
    for (int n = 0; n < NB_; n++) {
        const float* vd = vdiff + ((size_t)p * NB_ + n) * 3;
        float v0 = vd[0], v1 = vd[1], v2 = vd[2];
        vs0 += v0; vs1 += v1; vs2 += v2;
        int idx = nb[p * NB_ + n];
        if (idx > 0) {
            const float* Tn = Tm + ((size_t)b * P_ + (idx - 1)) * 9;
            a0 += Tn[0] * v0 + Tn[1] * v1 + Tn[2] * v2;
            a1 += Tn[3] * v0 + Tn[4] * v1 + Tn[5] * v2;
            a2 += Tn[6] * v0 + Tn[7] * v1 + Tn[8] * v2;
        }
    }
    a0 += Town[0] * vs0 + Town[1] * vs1 + Town[2] * vs2;
    a1 += Town[3] * vs0 + Town[4] * vs1 + Town[5] * vs2;
    a2 += Town[6] * vs0 + Town[7] * vs1 + Town[8] * vs2;
    bvecT[(size_t)(b * 3 + 0) * P_ + p] = a0;
    bvecT[(size_t)(b * 3 + 1) * P_ + p] = a1;
    bvecT[(size_t)(b * 3 + 2) * P_ + p] = a2;
}

// ------- Kernel 3: v[b,i,d] = sum_p recon[i,p] * bvec[b,p,d]  (M=K=10000, N=48)
// Block: 256 thr = 32 rowgroups x 8 colgroups; thread tile 4 rows x 6 cols.
// Each recon element loaded exactly once chip-wide (row-tile x K-chunk disjoint).
#define BM  128
#define KCH 1000
#define SK  10
__global__ __launch_bounds__(256) void gemm_kernel(const float* __restrict__ recon,
                                                   const float* __restrict__ bvecT,
                                                   float* __restrict__ out) {
    int rowbase = blockIdx.x * BM;
    int p0 = blockIdx.y * KCH;
    int tid = threadIdx.x;
    int cg = tid & 7;    // col group: 8 groups of 6 cols
    int rg = tid >> 3;   // row group: 32 groups of 4 rows
    int j0 = cg * 6;
    int r0 = rowbase + rg * 4;

    int rv[4];
#pragma unroll
    for (int m = 0; m < 4; m++) rv[m] = (r0 + m < P_) ? (r0 + m) : (P_ - 1);

    float acc[4][6];
#pragma unroll
    for (int m = 0; m < 4; m++)
#pragma unroll
        for (int j = 0; j < 6; j++) acc[m][j] = 0.0f;

    const float4* aptr[4];
#pragma unroll
    for (int m = 0; m < 4; m++) aptr[m] = (const float4*)(recon + (size_t)rv[m] * P_);
    const float4* bptr[6];
#pragma unroll
    for (int j = 0; j < 6; j++) bptr[j] = (const float4*)(bvecT + (size_t)(j0 + j) * P_);

    int p4beg = p0 >> 2;
    int p4end = (p0 + KCH) >> 2;
    for (int p4 = p4beg; p4 < p4end; ++p4) {
        float4 a[4], bb[6];
#pragma unroll
        for (int m = 0; m < 4; m++) a[m] = aptr[m][p4];
#pragma unroll
        for (int j = 0; j < 6; j++) bb[j] = bptr[j][p4];
#pragma unroll
        for (int m = 0; m < 4; m++)
#pragma unroll
            for (int j = 0; j < 6; j++) {
                acc[m][j] += a[m].x * bb[j].x;
                acc[m][j] += a[m].y * bb[j].y;
                acc[m][j] += a[m].z * bb[j].z;
                acc[m][j] += a[m].w * bb[j].w;
            }
    }

#pragma unroll
    for (int m = 0; m < 4; m++) {
        int r = r0 + m;
        if (r < P_) {
#pragma unroll
            for (int j = 0; j < 6; j++) {
                int jj = j0 + j;
                int b = jj / 3;
                int d = jj - b * 3;
                atomicAdd(&out[(size_t)b * P_ * 3 + (size_t)r * 3 + d], acc[m][j]);
            }
        }
    }
}

extern "C" void kernel_launch(void* const* d_in, const int* in_sizes, int n_in,
                              void* d_out, int out_size, void* d_ws, size_t ws_size,
                              hipStream_t stream) {
    const float* geo   = (const float*)d_in[0];
    const int*   nb    = (const int*)d_in[1];
    const float* recon = (const float*)d_in[2];
    const float* vdiff = (const float*)d_in[3];
    float* out = (float*)d_out;

    float* Tm    = (float*)d_ws;                         // B*P*9 floats = 5.76 MB
    float* bvecT = Tm + (size_t)B_ * P_ * 9;             // 48*P floats  = 1.92 MB

    int BP = B_ * P_;
    hipLaunchKernelGGL(ftoT_kernel, dim3((BP + 255) / 256), dim3(256), 0, stream, geo, Tm);
    hipLaunchKernelGGL(bvec_kernel, dim3((BP + 255) / 256), dim3(256), 0, stream, Tm, nb, vdiff, bvecT);
    hipMemsetAsync(out, 0, (size_t)out_size * sizeof(float), stream);
    hipLaunchKernelGGL(gemm_kernel, dim3((P_ + BM - 1) / BM, SK), dim3(256), 0, stream,
                       recon, bvecT, out);
}

// Round 2
// 772.587 us; speedup vs baseline: 1.8005x; 1.8005x over previous
//
#include <hip/hip_runtime.h>
#include <math.h>

#define B_  16
#define P_  10000
#define NB_ 10

// ---------------- Kernel 1: T = R(logr) @ S, per (b,p) ----------------
__global__ __launch_bounds__(256) void ftoT_kernel(const float* __restrict__ f,
                                                   float* __restrict__ Tm) {
    int t = blockIdx.x * blockDim.x + threadIdx.x;
    if (t >= B_ * P_) return;
    const float* fp = f + (size_t)t * 9;
    float x = fp[0], y = fp[1], z = fp[2];
    float s3 = fp[3], s4 = fp[4], s5 = fp[5], s6 = fp[6], s7 = fp[7], s8 = fp[8];
    float th2 = x * x + y * y + z * z;
    float R00, R01, R02, R10, R11, R12, R20, R21, R22;
    if (th2 == 0.0f) {
        R00 = 1; R01 = 0; R02 = 0;
        R10 = 0; R11 = 1; R12 = 0;
        R20 = 0; R21 = 0; R22 = 1;
    } else {
        float theta = sqrtf(th2);
        float inv = 1.0f / theta;
        float kx = x * inv, ky = y * inv, kz = z * inv;
        float st = sinf(theta);
        float omc = 1.0f - cosf(theta);
        R00 = 1.0f - omc * (kx * kx + ky * ky);
        R01 = kx * st - omc * (ky * kz);
        R02 = ky * st + omc * (kx * kz);
        R10 = -kx * st - omc * (ky * kz);
        R11 = 1.0f - omc * (kx * kx + kz * kz);
        R12 = kz * st - omc * (kx * ky);
        R20 = -ky * st + omc * (kx * kz);
        R21 = -kz * st - omc * (kx * ky);
        R22 = 1.0f - omc * (ky * ky + kz * kz);
    }
    float* o = Tm + (size_t)t * 9;
    o[0] = R00 * s3 + R01 * s4 + R02 * s5;
    o[1] = R00 * s4 + R01 * s6 + R02 * s7;
    o[2] = R00 * s5 + R01 * s7 + R02 * s8;
    o[3] = R10 * s3 + R11 * s4 + R12 * s5;
    o[4] = R10 * s4 + R11 * s6 + R12 * s7;
    o[5] = R10 * s5 + R11 * s7 + R12 * s8;
    o[6] = R20 * s3 + R21 * s4 + R22 * s5;
    o[7] = R20 * s4 + R21 * s6 + R22 * s7;
    o[8] = R20 * s5 + R21 * s7 + R22 * s8;
}

// ------- Kernel 2: bvec[b,p] = sum_n T_nb @ vdiff[p,n] + T_own @ sum_n vdiff[p,n]
// Output transposed: bvecT[(b*3+d)*P + p] for coalesced/stageable reads in GEMM.
__global__ __launch_bounds__(256) void bvec_kernel(const float* __restrict__ Tm,
                                                   const int* __restrict__ nb,
                                                   const float* __restrict__ vdiff,
                                                   float* __restrict__ bvecT) {
    int t = blockIdx.x * blockDim.x + threadIdx.x;
    if (t >= B_ * P_) return;
    int b = t / P_;
    int p = t - b * P_;
    const float* Town = Tm + (size_t)t * 9;
    float a0 = 0, a1 = 0, a2 = 0, vs0 = 0, vs1 = 0, vs2 = 0;
#pragma unroll
    for (int n = 0; n < NB_; n++) {
        const float* vd = vdiff + ((size_t)p * NB_ + n) * 3;
        float v0 = vd[0], v1 = vd[1], v2 = vd[2];
        vs0 += v0; vs1 += v1; vs2 += v2;
        int idx = nb[p * NB_ + n];
        if (idx > 0) {
            const float* Tn = Tm + ((size_t)b * P_ + (idx - 1)) * 9;
            a0 += Tn[0] * v0 + Tn[1] * v1 + Tn[2] * v2;
            a1 += Tn[3] * v0 + Tn[4] * v1 + Tn[5] * v2;
            a2 += Tn[6] * v0 + Tn[7] * v1 + Tn[8] * v2;
        }
    }
    a0 += Town[0] * vs0 + Town[1] * vs1 + Town[2] * vs2;
    a1 += Town[3] * vs0 + Town[4] * vs1 + Town[5] * vs2;
    a2 += Town[6] * vs0 + Town[7] * vs1 + Town[8] * vs2;
    bvecT[(size_t)(b * 3 + 0) * P_ + p] = a0;
    bvecT[(size_t)(b * 3 + 1) * P_ + p] = a1;
    bvecT[(size_t)(b * 3 + 2) * P_ + p] = a2;
}

// ------- Kernel 3: part[kz][j][r] = sum_{p in chunk kz} recon[r][p] * bvecT[j][p]
// One recon row per thread (lanes hit 64 distinct cache lines per wave-load ->
// deep MLP), all 48 columns accumulated in VGPRs, B-tile staged in LDS and read
// via wave-uniform broadcast (conflict-free). No atomics: partials + reduce.
#define BMR 250   // active rows per block (250 of 256 threads)
#define KT  100   // k-elements staged in LDS per stage (48*100*4B ~ 19.6KB padded)
__global__ __launch_bounds__(256, 4) void gemm_kernel(const float* __restrict__ recon,
                                                      const float* __restrict__ bvecT,
                                                      float* __restrict__ part,
                                                      int KCH) {
    __shared__ float bs[KT / 4][49][4];   // padded: staging writes 2-way max
    int tid = threadIdx.x;
    int r = blockIdx.x * BMR + tid;
    int k0 = blockIdx.y * KCH;
    int kend = k0 + KCH;
    if (kend > P_) kend = P_;
    bool active = (tid < BMR) && (r < P_);

    float acc[48];
#pragma unroll
    for (int j = 0; j < 48; j++) acc[j] = 0.0f;

    const float4* arow = (const float4*)(recon + (size_t)r * P_);

    for (int kt = k0; kt < kend; kt += KT) {
        __syncthreads();
        // stage 48 x KT B-values, coalesced global reads per j-row
        for (int c = tid; c < 48 * KT; c += 256) {
            int j = c / KT;
            int kk = c - j * KT;
            bs[kk >> 2][j][kk & 3] = bvecT[(size_t)j * P_ + kt + kk];
        }
        __syncthreads();
        if (active) {
            int k4 = (kt >> 2);
            float4 a_next = arow[k4];
            for (int s = 0; s < KT / 4; s++) {
                float4 a = a_next;
                if (s + 1 < KT / 4) a_next = arow[k4 + s + 1];  // prefetch
#pragma unroll
                for (int j = 0; j < 48; j++) {
                    float4 b = *(const float4*)&bs[s][j][0];   // broadcast read
                    acc[j] += a.x * b.x + a.y * b.y + a.z * b.z + a.w * b.w;
                }
            }
        }
    }

    if (active) {
        float* pp = part + (size_t)blockIdx.y * (48 * P_);
#pragma unroll
        for (int j = 0; j < 48; j++) pp[(size_t)j * P_ + r] = acc[j];
    }
}

// ------- Kernel 4: out[b][r][d] = sum_kz part[kz][(b*3+d)][r]
__global__ __launch_bounds__(256) void reduce_kernel(const float* __restrict__ part,
                                                     float* __restrict__ out, int SK) {
    int i = blockIdx.x * blockDim.x + threadIdx.x;
    if (i >= 48 * P_) return;
    float s = 0.0f;
    for (int z = 0; z < SK; z++) s += part[(size_t)z * (48 * P_) + i];
    int j = i / P_;
    int r = i - j * P_;
    int b = j / 3;
    int d = j - 3 * b;
    out[((size_t)b * P_ + r) * 3 + d] = s;
}

extern "C" void kernel_launch(void* const* d_in, const int* in_sizes, int n_in,
                              void* d_out, int out_size, void* d_ws, size_t ws_size,
                              hipStream_t stream) {
    const float* geo   = (const float*)d_in[0];
    const int*   nb    = (const int*)d_in[1];
    const float* recon = (const float*)d_in[2];
    const float* vdiff = (const float*)d_in[3];
    float* out = (float*)d_out;

    float* Tm    = (float*)d_ws;                          // B*P*9  = 5.76 MB
    float* bvecT = Tm + (size_t)B_ * P_ * 9;              // 48*P   = 1.92 MB
    float* part  = bvecT + (size_t)48 * P_;               // SK * 1.92 MB

    // adaptive K-split based on workspace size (each partial slab = 48*P floats)
    size_t base_floats = (size_t)B_ * P_ * 9 + (size_t)48 * P_;
    size_t ws_floats = ws_size / 4;
    size_t avail = (ws_floats > base_floats) ? (ws_floats - base_floats) : 0;
    int SK = (int)(avail / ((size_t)48 * P_));
    if (SK > 20) SK = 20;
    if (SK < 1) SK = 1;
    int KCH = ((P_ + SK - 1) / SK + KT - 1) / KT * KT;    // multiple of KT
    int SKeff = (P_ + KCH - 1) / KCH;

    int BP = B_ * P_;
    hipLaunchKernelGGL(ftoT_kernel, dim3((BP + 255) / 256), dim3(256), 0, stream, geo, Tm);
    hipLaunchKernelGGL(bvec_kernel, dim3((BP + 255) / 256), dim3(256), 0, stream,
                       Tm, nb, vdiff, bvecT);
    hipLaunchKernelGGL(gemm_kernel, dim3((P_ + BMR - 1) / BMR, SKeff), dim3(256), 0, stream,
                       recon, bvecT, part, KCH);
    hipLaunchKernelGGL(reduce_kernel, dim3((48 * P_ + 255) / 256), dim3(256), 0, stream,
                       part, out, SKeff);
}

// Round 3
// 566.995 us; speedup vs baseline: 2.4533x; 1.3626x over previous
//
#include <hip/hip_runtime.h>
#include <math.h>

#define B_    16
#define P_    10000
#define NB_   10
#define KBTOT 313      // ceil(P_/32) k-blocks of 32
#define KBPAD 328      // padded k-block count (zero-filled tail)
#define NSMAX 8        // max K-splits

typedef __attribute__((ext_vector_type(8))) short bf16x8;   // 8 bf16 (4 VGPRs)
typedef __attribute__((ext_vector_type(4))) float f32x4;    // MFMA accumulator

static __device__ __forceinline__ unsigned short f2bf(float f) {
    // RNE float -> bf16 bits
    unsigned u = __float_as_uint(f);
    u += 0x7fffu + ((u >> 16) & 1u);
    return (unsigned short)(u >> 16);
}

// ---------------- Kernel 1: T = R(logr) @ S ----------------
// Thread t: p = t>>4, b = t&15. Output layout Tm2[p][b][12] (48B-padded rows
// so the bvec gather can use aligned float4 loads, 16 lanes = 768B contiguous).
__global__ __launch_bounds__(256) void ftoT_kernel(const float* __restrict__ f,
                                                   float* __restrict__ Tm2) {
    int t = blockIdx.x * blockDim.x + threadIdx.x;
    if (t >= B_ * P_) return;
    int p = t >> 4, b = t & 15;
    const float* fp = f + ((size_t)b * P_ + p) * 9;
    float x = fp[0], y = fp[1], z = fp[2];
    float s3 = fp[3], s4 = fp[4], s5 = fp[5], s6 = fp[6], s7 = fp[7], s8 = fp[8];
    float th2 = x * x + y * y + z * z;
    float R00, R01, R02, R10, R11, R12, R20, R21, R22;
    if (th2 == 0.0f) {
        R00 = 1; R01 = 0; R02 = 0; R10 = 0; R11 = 1; R12 = 0; R20 = 0; R21 = 0; R22 = 1;
    } else {
        float theta = sqrtf(th2);
        float inv = 1.0f / theta;
        float kx = x * inv, ky = y * inv, kz = z * inv;
        float st = sinf(theta);
        float omc = 1.0f - cosf(theta);
        R00 = 1.0f - omc * (kx * kx + ky * ky);
        R01 = kx * st - omc * (ky * kz);
        R02 = ky * st + omc * (kx * kz);
        R10 = -kx * st - omc * (ky * kz);
        R11 = 1.0f - omc * (kx * kx + kz * kz);
        R12 = kz * st - omc * (kx * ky);
        R20 = -ky * st + omc * (kx * kz);
        R21 = -kz * st - omc * (kx * ky);
        R22 = 1.0f - omc * (ky * ky + kz * kz);
    }
    float* o = Tm2 + (size_t)t * 12;
    o[0] = R00 * s3 + R01 * s4 + R02 * s5;
    o[1] = R00 * s4 + R01 * s6 + R02 * s7;
    o[2] = R00 * s5 + R01 * s7 + R02 * s8;
    o[3] = R10 * s3 + R11 * s4 + R12 * s5;
    o[4] = R10 * s4 + R11 * s6 + R12 * s7;
    o[5] = R10 * s5 + R11 * s7 + R12 * s8;
    o[6] = R20 * s3 + R21 * s4 + R22 * s5;
    o[7] = R20 * s4 + R21 * s6 + R22 * s7;
    o[8] = R20 * s5 + R21 * s7 + R22 * s8;
    o[9] = 0.0f; o[10] = 0.0f; o[11] = 0.0f;
}

// ------- Kernel 2: bvec + pack into MFMA B-fragment layout (bf16) -------
// tid: pl = tid>>4 (16 p per block), bl = tid&15. Neighbor idx shared across
// the 16 b-lanes -> gather of T[idx][b][.] is one 768B contiguous segment.
// Bf[kb][t][lane][i] = B[k = kb*32 + (lane>>4)*8 + i][n = lane&15] where
// global col j = t*16 + n = b*3+d, row k = p.
__global__ __launch_bounds__(256) void bvec_kernel(const float* __restrict__ Tm2,
                                                   const int* __restrict__ nb,
                                                   const float* __restrict__ vdiff,
                                                   unsigned short* __restrict__ Bf) {
    int tid = threadIdx.x;
    int bl = tid & 15, pl = tid >> 4;
    int p = blockIdx.x * 16 + pl;
    if (p >= P_) return;

    const float4* Tow = (const float4*)(Tm2 + ((size_t)p * 16 + bl) * 12);
    float4 o0 = Tow[0], o1 = Tow[1], o2 = Tow[2];

    float a0 = 0, a1 = 0, a2 = 0, vs0 = 0, vs1 = 0, vs2 = 0;
#pragma unroll
    for (int n = 0; n < NB_; n++) {
        int idx = nb[p * NB_ + n];
        const float* vd = vdiff + ((size_t)p * NB_ + n) * 3;
        float v0 = vd[0], v1 = vd[1], v2 = vd[2];
        vs0 += v0; vs1 += v1; vs2 += v2;
        if (idx > 0) {
            const float4* Tp = (const float4*)(Tm2 + ((size_t)(idx - 1) * 16 + bl) * 12);
            float4 q0 = Tp[0], q1 = Tp[1], q2 = Tp[2];
            a0 += q0.x * v0 + q0.y * v1 + q0.z * v2;
            a1 += q0.w * v0 + q1.x * v1 + q1.y * v2;
            a2 += q1.z * v0 + q1.w * v1 + q2.x * v2;
        }
    }
    a0 += o0.x * vs0 + o0.y * vs1 + o0.z * vs2;
    a1 += o0.w * vs0 + o1.x * vs1 + o1.y * vs2;
    a2 += o1.z * vs0 + o1.w * vs1 + o2.x * vs2;

    int kb = p >> 5, ii = p & 7, quad = (p >> 3) & 3;
    float vals[3] = {a0, a1, a2};
#pragma unroll
    for (int d = 0; d < 3; d++) {
        int j = bl * 3 + d;
        int t = j >> 4;
        int ln = quad * 16 + (j & 15);
        Bf[(((size_t)kb * 3 + t) * 64 + ln) * 8 + ii] = f2bf(vals[d]);
    }
}

// ------- Kernel 3: MFMA GEMM. Wave = 16 rows x 48 cols, no LDS. -------
// A: recon fp32 streamed from HBM, converted to bf16 in-register.
// B: pre-packed fragments (L2-resident, one dwordx4 per frag).
// K-split over blockIdx.y into fp32 partial slabs part[y][j][r].
__global__ __launch_bounds__(256) void gemm_mfma(const float* __restrict__ recon,
                                                 const unsigned short* __restrict__ Bf,
                                                 float* __restrict__ part, int KBC) {
    int l = threadIdx.x & 63;
    int w = threadIdx.x >> 6;
    int r0 = (blockIdx.x * 4 + w) * 16;
    if (r0 >= P_) return;                    // tail waves (P_ % 16 == 0)
    int y = blockIdx.y;
    int kb0 = y * KBC;
    int n = l & 15, quad = l >> 4;
    int r = r0 + n;
    const float* ap = recon + (size_t)r * P_;
    const bf16x8* Bv = (const bf16x8*)Bf;

    f32x4 acc0 = {0, 0, 0, 0}, acc1 = {0, 0, 0, 0}, acc2 = {0, 0, 0, 0};

#pragma unroll 2
    for (int kb = kb0; kb < kb0 + KBC; ++kb) {
        int k = kb * 32 + quad * 8;
        bf16x8 a;
        if (k < P_) {                        // k is a multiple of 8; full 8 valid
            const float4* apk = (const float4*)(ap + k);
            float4 x0 = apk[0], x1 = apk[1];
            a[0] = (short)f2bf(x0.x); a[1] = (short)f2bf(x0.y);
            a[2] = (short)f2bf(x0.z); a[3] = (short)f2bf(x0.w);
            a[4] = (short)f2bf(x1.x); a[5] = (short)f2bf(x1.y);
            a[6] = (short)f2bf(x1.z); a[7] = (short)f2bf(x1.w);
        } else {
            a = (bf16x8)0;
        }
        bf16x8 b0 = Bv[((size_t)kb * 3 + 0) * 64 + l];
        bf16x8 b1 = Bv[((size_t)kb * 3 + 1) * 64 + l];
        bf16x8 b2 = Bv[((size_t)kb * 3 + 2) * 64 + l];
        acc0 = __builtin_amdgcn_mfma_f32_16x16x32_bf16(a, b0, acc0, 0, 0, 0);
        acc1 = __builtin_amdgcn_mfma_f32_16x16x32_bf16(a, b1, acc1, 0, 0, 0);
        acc2 = __builtin_amdgcn_mfma_f32_16x16x32_bf16(a, b2, acc2, 0, 0, 0);
    }

    // C/D: col = lane&15, row = (lane>>4)*4 + reg  -> float4 store per tile
    float* base = part + (size_t)y * (48 * P_);
    int rs = r0 + quad * 4;
    f32x4 accs[3] = {acc0, acc1, acc2};
#pragma unroll
    for (int t = 0; t < 3; t++) {
        int j = t * 16 + n;
        float4 st = make_float4(accs[t][0], accs[t][1], accs[t][2], accs[t][3]);
        *(float4*)(base + (size_t)j * P_ + rs) = st;
    }
}

// ------- Kernel 4: out[b][r][d] = sum_y part[y][j=b*3+d][r] -------
__global__ __launch_bounds__(256) void reduce_kernel(const float* __restrict__ part,
                                                     float* __restrict__ out, int NS) {
    int i = blockIdx.x * blockDim.x + threadIdx.x;
    if (i >= 48 * P_) return;
    float s = 0.0f;
    for (int z = 0; z < NS; z++) s += part[(size_t)z * (48 * P_) + i];
    int j = i / P_;
    int r = i - j * P_;
    int b = j / 3;
    int d = j - 3 * b;
    out[((size_t)b * P_ + r) * 3 + d] = s;
}

extern "C" void kernel_launch(void* const* d_in, const int* in_sizes, int n_in,
                              void* d_out, int out_size, void* d_ws, size_t ws_size,
                              hipStream_t stream) {
    const float* geo   = (const float*)d_in[0];
    const int*   nb    = (const int*)d_in[1];
    const float* recon = (const float*)d_in[2];
    const float* vdiff = (const float*)d_in[3];
    float* out = (float*)d_out;

    // workspace partition
    const size_t Tm2F = (size_t)B_ * P_ * 12;                 // 1.92M floats (7.68 MB)
    const size_t BfU  = (size_t)KBPAD * 3 * 64 * 8;           // 503808 ushorts
    const size_t BfF  = (BfU + 1) / 2;                        // in float units
    float*          Tm2  = (float*)d_ws;
    unsigned short* Bf   = (unsigned short*)(Tm2 + Tm2F);
    float*          part = Tm2 + Tm2F + BfF;

    // adaptive K-split (each partial slab = 48*P_ floats = 1.92 MB)
    size_t ws_floats = ws_size / 4;
    size_t used = Tm2F + BfF;
    size_t avail = (ws_floats > used) ? (ws_floats - used) : 0;
    int NS = (int)(avail / ((size_t)48 * P_));
    if (NS > NSMAX) NS = NSMAX;
    if (NS < 1) NS = 1;
    int KBC = (320 + NS - 1) / NS;     // k-blocks per split (320 = padded, /8 clean)

    hipMemsetAsync(Bf, 0, BfU * sizeof(unsigned short), stream);
    int BP = B_ * P_;
    hipLaunchKernelGGL(ftoT_kernel, dim3((BP + 255) / 256), dim3(256), 0, stream, geo, Tm2);
    hipLaunchKernelGGL(bvec_kernel, dim3((P_ + 15) / 16), dim3(256), 0, stream,
                       Tm2, nb, vdiff, Bf);
    hipLaunchKernelGGL(gemm_mfma, dim3((P_ + 63) / 64, NS), dim3(256), 0, stream,
                       recon, Bf, part, KBC);
    hipLaunchKernelGGL(reduce_kernel, dim3((48 * P_ + 255) / 256), dim3(256), 0, stream,
                       part, out, NS);
}